// Round 10
// baseline (100.563 us; speedup 1.0000x reference)
//
#include <hip/hip_runtime.h>
#include <hip/hip_bf16.h>

#define N_POS 4096
#define C_IN 64
#define IC 32
#define L2E 1.4426950408889634f

typedef float f32x16 __attribute__((ext_vector_type(16)));
typedef short bf16x8 __attribute__((ext_vector_type(8)));
typedef unsigned int uint;
typedef uint uint4v __attribute__((ext_vector_type(4)));
typedef unsigned short ushort;

static __device__ __forceinline__ ushort f2bf(float f) {
    __hip_bfloat16 h = __float2bfloat16(f);
    return __builtin_bit_cast(ushort, h);
}
static __device__ __forceinline__ float bf2f(ushort u) {
    uint v = ((uint)u) << 16;
    return __builtin_bit_cast(float, v);
}
static __device__ __forceinline__ uint packbf2(float lo, float hi) {
    return (uint)f2bf(lo) | ((uint)f2bf(hi) << 16);
}
// truncating pack: 2 VALU ops; P>=0 feeds a ratio -> bias cancels to ~0.2%
static __device__ __forceinline__ uint packtrunc(float lo, float hi) {
    uint l = __builtin_bit_cast(uint, lo);
    uint h = __builtin_bit_cast(uint, hi);
    return (l >> 16) | (h & 0xffff0000u);
}

// ---------------- Stage A: projections -> bf16 MFMA layouts ----------------
// grid (256, 2): gy = half16. All 3 projections per block: x read ONCE per half.
// theta weights/bias pre-scaled by log2(e) at LDS load.
__global__ __launch_bounds__(128) void proj_kernel(
    const float* __restrict__ x,
    const float* __restrict__ g_w, const float* __restrict__ g_b,
    const float* __restrict__ th_w, const float* __restrict__ th_b,
    const float* __restrict__ ph_w, const float* __restrict__ ph_b,
    ushort* __restrict__ gcn, ushort* __restrict__ tht, ushort* __restrict__ pht)
{
    int half = blockIdx.y;
    __shared__ float w[48][64];
    __shared__ float bias[48];
    int tid = threadIdx.x;
    for (int i = tid; i < 3072; i += 128) {
        int r = i >> 6, c = i & 63;
        const float* src = (r < 16) ? g_w : (r < 32) ? th_w : ph_w;
        float v = src[((r & 15) + half * 16) * 64 + c];
        if (r >= 16 && r < 32) v *= L2E;
        w[r][c] = v;
    }
    if (tid < 48) {
        const float* bsrc = (tid < 16) ? g_b : (tid < 32) ? th_b : ph_b;
        float v = bsrc[(tid & 15) + half * 16];
        if (tid >= 16 && tid < 32) v *= L2E;
        bias[tid] = v;
    }
    __syncthreads();

    int ng = blockIdx.x * 128 + tid;
    int b = ng >> 12, n = ng & 4095;
    const float* xb = x + (size_t)b * C_IN * N_POS + n;
    float xr[64];
    #pragma unroll
    for (int c = 0; c < 64; c++) xr[c] = xb[(size_t)c * N_POS];

    float acc[48];
    #pragma unroll
    for (int o = 0; o < 48; o++) {
        float a = bias[o];
        const float4* w4 = (const float4*)w[o];
        #pragma unroll
        for (int c4 = 0; c4 < 16; c4++) {
            float4 wv = w4[c4];
            a += wv.x * xr[c4*4+0] + wv.y * xr[c4*4+1]
               + wv.z * xr[c4*4+2] + wv.w * xr[c4*4+3];
        }
        acc[o] = a;
    }

    // g -> [b][c][n]
    #pragma unroll
    for (int c = 0; c < 16; c++)
        gcn[((size_t)(b * IC + half * 16 + c)) * N_POS + n] = f2bf(acc[c]);
    // theta -> [b][n][c] (pre-scaled), phi -> [b][n][c]
    {
        ushort* dst = tht + ((size_t)(b * N_POS + n)) * IC + half * 16;
        uint4v pk0, pk1;
        #pragma unroll
        for (int i = 0; i < 4; i++) pk0[i] = packbf2(acc[16 + 2*i], acc[16 + 2*i+1]);
        #pragma unroll
        for (int i = 0; i < 4; i++) pk1[i] = packbf2(acc[24 + 2*i], acc[24 + 2*i+1]);
        *(uint4v*)dst = pk0;
        *(uint4v*)(dst + 8) = pk1;
    }
    {
        ushort* dst = pht + ((size_t)(b * N_POS + n)) * IC + half * 16;
        uint4v pk0, pk1;
        #pragma unroll
        for (int i = 0; i < 4; i++) pk0[i] = packbf2(acc[32 + 2*i], acc[32 + 2*i+1]);
        #pragma unroll
        for (int i = 0; i < 4; i++) pk1[i] = packbf2(acc[40 + 2*i], acc[40 + 2*i+1]);
        *(uint4v*)dst = pk0;
        *(uint4v*)(dst + 8) = pk1;
    }
}

// -------- mb prep: keys (mbt) pre-scaled by 32^-0.5 * log2e ----------------
__global__ __launch_bounds__(256) void mbprep_kernel(
    const float* __restrict__ mb, ushort* __restrict__ mbt,
    ushort* __restrict__ mbb)
{
    int i = blockIdx.x * 256 + threadIdx.x;   // 8192
    int c = i >> 8, k = i & 255;
    float v = mb[i];
    mbb[i] = f2bf(v);
    mbt[k * 32 + c] = f2bf(v * (0.17677669529663687f * L2E));
}

// ------------- Stage B: non-local attention, q-paired, pi-permuted ----------
// grid 1024 blocks x 4 waves: block = (b, qpair, mhalf); wave = 512 keys,
// computing TWO 32-query tiles (amortizes phi/g loads 2x).
// pi (swap 4-blocks 1<->2 mod 16) on phi rows makes lane key-sets contiguous:
// g B-frags become two b128 loads. Identical math to verified R6 sigma form.
__global__ __launch_bounds__(256) void attn_kernel(
    const ushort* __restrict__ tht, const ushort* __restrict__ pht,
    const ushort* __restrict__ gcn, float* __restrict__ yp,
    float* __restrict__ dnm)
{
    __shared__ float redY[4][2][32][32];   // 32 KB
    __shared__ float redD[4][2][32];
    int tid = threadIdx.x;
    int s = tid >> 6, lane = tid & 63;
    int bid = blockIdx.x;
    int b = bid & 7;                 // batch -> XCD locality
    int rest = bid >> 3;             // 0..127
    int qp = rest >> 1;              // 0..63
    int half = rest & 1;
    int q0 = qp * 64;
    int mbase = (half * 4 + s) * 512;
    int cl = lane & 31, h = lane >> 5;
    int t4 = (cl >> 2) & 3;
    int pcl = (t4 == 1 || t4 == 2) ? (cl ^ 12) : cl;   // pi row permutation

    const ushort* thpA = tht + ((size_t)(b * N_POS + q0 + cl)) * IC + 8 * h;
    bf16x8 thA0 = *(const bf16x8*)thpA;
    bf16x8 thA1 = *(const bf16x8*)(thpA + 16);
    const ushort* thpB = thpA + 32 * IC;
    bf16x8 thB0 = *(const bf16x8*)thpB;
    bf16x8 thB1 = *(const bf16x8*)(thpB + 16);

    const ushort* phbase = pht + (size_t)b * N_POS * IC;
    const ushort* gbase  = gcn + ((size_t)(b * IC + cl)) * N_POS;

    f32x16 yA0, yA1, yB0, yB1, zero;
    #pragma unroll
    for (int i = 0; i < 16; i++) {
        yA0[i] = 0.f; yA1[i] = 0.f; yB0[i] = 0.f; yB1[i] = 0.f; zero[i] = 0.f;
    }
    float sumeA = 0.f, sumeB = 0.f;

    #pragma unroll 2
    for (int mt = 0; mt < 16; ++mt) {
        int m0 = mbase + mt * 32;
        const ushort* php = phbase + ((size_t)(m0 + pcl)) * IC + 8 * h;
        bf16x8 ph0 = *(const bf16x8*)php;
        bf16x8 ph1 = *(const bf16x8*)(php + 16);
        // contiguous g B-frags (keys m0+8h.. and m0+16+8h..): two b128
        const ushort* gp = gbase + m0 + 8 * h;
        bf16x8 g0 = *(const bf16x8*)gp;
        bf16x8 g1 = *(const bf16x8*)(gp + 16);

        // q-tile A: S^T then exp2 (theta pre-scaled by log2e)
        f32x16 sv = __builtin_amdgcn_mfma_f32_32x32x16_bf16(ph0, thA0, zero, 0, 0, 0);
        sv = __builtin_amdgcn_mfma_f32_32x32x16_bf16(ph1, thA1, sv, 0, 0, 0);
        uint wA[8];
        #pragma unroll
        for (int i = 0; i < 8; i++) {
            float p0 = __builtin_amdgcn_exp2f(sv[2*i]);
            float p1 = __builtin_amdgcn_exp2f(sv[2*i+1]);
            sumeA += p0 + p1;
            wA[i] = packtrunc(p0, p1);
        }
        // q-tile B
        f32x16 sw = __builtin_amdgcn_mfma_f32_32x32x16_bf16(ph0, thB0, zero, 0, 0, 0);
        sw = __builtin_amdgcn_mfma_f32_32x32x16_bf16(ph1, thB1, sw, 0, 0, 0);
        uint wB[8];
        #pragma unroll
        for (int i = 0; i < 8; i++) {
            float p0 = __builtin_amdgcn_exp2f(sw[2*i]);
            float p1 = __builtin_amdgcn_exp2f(sw[2*i+1]);
            sumeB += p0 + p1;
            wB[i] = packtrunc(p0, p1);
        }

        uint4v aA0, aA1, aB0, aB1;
        aA0[0] = wA[0]; aA0[1] = wA[1]; aA0[2] = wA[2]; aA0[3] = wA[3];
        aA1[0] = wA[4]; aA1[1] = wA[5]; aA1[2] = wA[6]; aA1[3] = wA[7];
        aB0[0] = wB[0]; aB0[1] = wB[1]; aB0[2] = wB[2]; aB0[3] = wB[3];
        aB1[0] = wB[4]; aB1[1] = wB[5]; aB1[2] = wB[6]; aB1[3] = wB[7];

        yA0 = __builtin_amdgcn_mfma_f32_32x32x16_bf16(
            __builtin_bit_cast(bf16x8, aA0), g0, yA0, 0, 0, 0);
        yA1 = __builtin_amdgcn_mfma_f32_32x32x16_bf16(
            __builtin_bit_cast(bf16x8, aA1), g1, yA1, 0, 0, 0);
        yB0 = __builtin_amdgcn_mfma_f32_32x32x16_bf16(
            __builtin_bit_cast(bf16x8, aB0), g0, yB0, 0, 0, 0);
        yB1 = __builtin_amdgcn_mfma_f32_32x32x16_bf16(
            __builtin_bit_cast(bf16x8, aB1), g1, yB1, 0, 0, 0);
    }

    // stash partials in LDS (both q-tiles)
    sumeA += __shfl_xor(sumeA, 32);
    sumeB += __shfl_xor(sumeB, 32);
    if (lane < 32) { redD[s][0][cl] = sumeA; redD[s][1][cl] = sumeB; }
    #pragma unroll
    for (int r = 0; r < 16; r++) {
        int q = (r & 3) + 8 * (r >> 2) + 4 * h;
        redY[s][0][q][cl] = yA0[r] + yA1[r];
        redY[s][1][q][cl] = yB0[r] + yB1[r];
    }
    __syncthreads();

    // block reduce over the 4 waves -> fp32 partials for (b, qp*2+j, half)
    int q = tid >> 3, c4 = tid & 7;
    #pragma unroll
    for (int j = 0; j < 2; j++) {
        float den = redD[0][j][q] + redD[1][j][q] + redD[2][j][q] + redD[3][j][q];
        float4 v0 = *(const float4*)&redY[0][j][q][c4 * 4];
        float4 v1 = *(const float4*)&redY[1][j][q][c4 * 4];
        float4 v2 = *(const float4*)&redY[2][j][q][c4 * 4];
        float4 v3 = *(const float4*)&redY[3][j][q][c4 * 4];
        float4 vv;
        vv.x = v0.x + v1.x + v2.x + v3.x;
        vv.y = v0.y + v1.y + v2.y + v3.y;
        vv.z = v0.z + v1.z + v2.z + v3.z;
        vv.w = v0.w + v1.w + v2.w + v3.w;
        size_t t = ((size_t)(b * 128 + qp * 2 + j)) * 2 + half;
        *(float4*)(yp + t * 1024 + q * 32 + c4 * 4) = vv;
        if (c4 == 0) dnm[t * 32 + q] = den;
    }
}

// ------- Stage C: mb attention -> y1[b][n][32] (pi + b128 B-loads) ----------
__global__ __launch_bounds__(256) void mb_attn_kernel(
    const ushort* __restrict__ pht, const ushort* __restrict__ mbt,
    const ushort* __restrict__ mbb, ushort* __restrict__ y1)
{
    int tid = threadIdx.x;
    int widx = tid >> 6, lane = tid & 63;
    int gwid = blockIdx.x * 4 + widx;      // 0..1023
    int b = gwid >> 7, qt = gwid & 127;
    int q0 = qt * 32;
    int cl = lane & 31, h = lane >> 5;
    int t4 = (cl >> 2) & 3;
    int pcl = (t4 == 1 || t4 == 2) ? (cl ^ 12) : cl;

    const ushort* php = pht + ((size_t)(b * N_POS + q0 + cl)) * IC + 8 * h;
    bf16x8 qf0 = *(const bf16x8*)php;
    bf16x8 qf1 = *(const bf16x8*)(php + 16);

    f32x16 yaccA, yaccB, zero;
    #pragma unroll
    for (int i = 0; i < 16; i++) { yaccA[i] = 0.f; yaccB[i] = 0.f; zero[i] = 0.f; }
    float sume = 0.f;

    #pragma unroll 2
    for (int kt = 0; kt < 8; ++kt) {
        int k0 = kt * 32;
        const ushort* ap = mbt + ((size_t)(k0 + pcl)) * IC + 8 * h;
        bf16x8 af0 = *(const bf16x8*)ap;
        bf16x8 af1 = *(const bf16x8*)(ap + 16);
        const ushort* bp = mbb + (size_t)cl * 256 + k0 + 8 * h;
        bf16x8 bf0 = *(const bf16x8*)bp;
        bf16x8 bf1 = *(const bf16x8*)(bp + 16);

        f32x16 sv = __builtin_amdgcn_mfma_f32_32x32x16_bf16(af0, qf0, zero, 0, 0, 0);
        sv = __builtin_amdgcn_mfma_f32_32x32x16_bf16(af1, qf1, sv, 0, 0, 0);

        uint w[8];
        #pragma unroll
        for (int i = 0; i < 8; i++) {
            float p0 = __builtin_amdgcn_exp2f(sv[2*i]);
            float p1 = __builtin_amdgcn_exp2f(sv[2*i+1]);
            sume += p0 + p1;
            w[i] = packtrunc(p0, p1);
        }
        uint4v a0, a1;
        a0[0] = w[0]; a0[1] = w[1]; a0[2] = w[2]; a0[3] = w[3];
        a1[0] = w[4]; a1[1] = w[5]; a1[2] = w[6]; a1[3] = w[7];

        yaccA = __builtin_amdgcn_mfma_f32_32x32x16_bf16(
            __builtin_bit_cast(bf16x8, a0), bf0, yaccA, 0, 0, 0);
        yaccB = __builtin_amdgcn_mfma_f32_32x32x16_bf16(
            __builtin_bit_cast(bf16x8, a1), bf1, yaccB, 0, 0, 0);
    }

    sume += __shfl_xor(sume, 32);          // lane q (0..31) holds denom[q]
    ushort* ybase = y1 + ((size_t)(b * N_POS + q0)) * 32;
    #pragma unroll
    for (int r = 0; r < 16; r++) {
        int q = (r & 3) + 8 * (r >> 2) + 4 * h;
        float d = __shfl(sume, q);
        ybase[q * 32 + cl] = f2bf((yaccA[r] + yaccB[r]) / d);
    }
}

// ------------- Stage D: combine halves, normalize, W/Wz1 matmul + x ---------
__global__ __launch_bounds__(128) void out_kernel(
    const float* __restrict__ x,
    const float* __restrict__ Ww, const float* __restrict__ Wb,
    const float* __restrict__ Wzw, const float* __restrict__ Wzb,
    const float* __restrict__ yp, const float* __restrict__ dnm,
    const ushort* __restrict__ y1, float* __restrict__ out)
{
    int oh = blockIdx.y;
    __shared__ float sW[32][32], sWz[32][32];
    __shared__ float sb[32];
    int tid = threadIdx.x;
    for (int i = tid; i < 1024; i += 128) {
        int o = i >> 5, c = i & 31;
        sW[o][c]  = Ww[(oh * 32 + o) * 32 + c];
        sWz[o][c] = Wzw[(oh * 32 + o) * 32 + c];
    }
    if (tid < 32) sb[tid] = Wb[oh * 32 + tid] + Wzb[oh * 32 + tid];
    __syncthreads();

    int ng = blockIdx.x * 128 + tid;
    int b = ng >> 12, n = ng & 4095;
    int qt = n >> 5, q = n & 31;
    size_t t0 = ((size_t)(b * 128 + qt)) * 2;
    float inv = 1.f / (dnm[t0 * 32 + q] + dnm[t0 * 32 + 32 + q]);

    const float* yp0 = yp + t0 * 1024 + q * 32;
    const float* yp1 = yp0 + 1024;
    float yv[32], y1v[32];
    #pragma unroll
    for (int c4 = 0; c4 < 8; c4++) {
        float4 v0 = ((const float4*)yp0)[c4];
        float4 v1 = ((const float4*)yp1)[c4];
        yv[c4*4+0] = (v0.x + v1.x) * inv;
        yv[c4*4+1] = (v0.y + v1.y) * inv;
        yv[c4*4+2] = (v0.z + v1.z) * inv;
        yv[c4*4+3] = (v0.w + v1.w) * inv;
    }
    const ushort* y1p = y1 + ((size_t)(b * N_POS + n)) * 32;
    #pragma unroll
    for (int i8 = 0; i8 < 4; i8++) {
        bf16x8 v = *(const bf16x8*)(y1p + i8 * 8);
        #pragma unroll
        for (int j = 0; j < 8; j++) y1v[i8 * 8 + j] = bf2f((ushort)v[j]);
    }

    const float* xb = x   + ((size_t)(b * C_IN + oh * 32)) * N_POS + n;
    float*       ob = out + ((size_t)(b * C_IN + oh * 32)) * N_POS + n;
    for (int o = 0; o < 32; o++) {
        float acc = sb[o] + xb[(size_t)o * N_POS];
        const float4* w4  = (const float4*)sW[o];
        const float4* wz4 = (const float4*)sWz[o];
        #pragma unroll
        for (int c4 = 0; c4 < 8; c4++) {
            float4 a = w4[c4], z = wz4[c4];
            acc += a.x * yv[c4*4+0] + a.y * yv[c4*4+1] + a.z * yv[c4*4+2] + a.w * yv[c4*4+3];
            acc += z.x * y1v[c4*4+0] + z.y * y1v[c4*4+1] + z.z * y1v[c4*4+2] + z.w * y1v[c4*4+3];
        }
        ob[(size_t)o * N_POS] = acc;
    }
}

extern "C" void kernel_launch(void* const* d_in, const int* in_sizes, int n_in,
                              void* d_out, int out_size, void* d_ws, size_t ws_size,
                              hipStream_t stream) {
    const float* x    = (const float*)d_in[0];
    const float* g_w  = (const float*)d_in[1];
    const float* g_b  = (const float*)d_in[2];
    const float* th_w = (const float*)d_in[3];
    const float* th_b = (const float*)d_in[4];
    const float* ph_w = (const float*)d_in[5];
    const float* ph_b = (const float*)d_in[6];
    const float* W_w  = (const float*)d_in[7];
    const float* W_b  = (const float*)d_in[8];
    const float* Wz_w = (const float*)d_in[9];
    const float* Wz_b = (const float*)d_in[10];
    const float* mb   = (const float*)d_in[11];
    float* out = (float*)d_out;

    char* w = (char*)d_ws;
    ushort* tht = (ushort*)w;                        // 2 MB
    ushort* pht = (ushort*)(w + (2u << 20));         // 2 MB
    ushort* gcn = (ushort*)(w + (4u << 20));         // 2 MB
    ushort* mbt = (ushort*)(w + (6u << 20));         // 16 KB
    ushort* mbb = (ushort*)(w + (6u << 20) + 16384); // 16 KB
    ushort* y1  = (ushort*)(w + (7u << 20));         // 2 MB  [b][n][32]
    float*  yp  = (float*)(w + (9u << 20));          // 8 MB  [b*128+qt][2][1024]
    float*  dnm = (float*)(w + (17u << 20));         // 256 KB

    proj_kernel<<<dim3(256, 2), 128, 0, stream>>>(x, g_w, g_b, th_w, th_b,
                                                  ph_w, ph_b, gcn, tht, pht);
    mbprep_kernel<<<32, 256, 0, stream>>>(mb, mbt, mbb);
    attn_kernel<<<1024, 256, 0, stream>>>(tht, pht, gcn, yp, dnm);
    mb_attn_kernel<<<256, 256, 0, stream>>>(pht, mbt, mbb, y1);
    out_kernel<<<dim3(256, 2), 128, 0, stream>>>(x, W_w, W_b, Wz_w, Wz_b,
                                                 yp, dnm, y1, out);
}

// Round 11
// 88.742 us; speedup vs baseline: 1.1332x; 1.1332x over previous
//
#include <hip/hip_runtime.h>
#include <hip/hip_bf16.h>

#define N_POS 4096
#define C_IN 64
#define IC 32
#define L2E 1.4426950408889634f

typedef float f32x16 __attribute__((ext_vector_type(16)));
typedef short bf16x8 __attribute__((ext_vector_type(8)));
typedef unsigned int uint;
typedef uint uint4v __attribute__((ext_vector_type(4)));
typedef unsigned short ushort;

static __device__ __forceinline__ ushort f2bf(float f) {
    __hip_bfloat16 h = __float2bfloat16(f);
    return __builtin_bit_cast(ushort, h);
}
static __device__ __forceinline__ float bf2f(ushort u) {
    uint v = ((uint)u) << 16;
    return __builtin_bit_cast(float, v);
}
static __device__ __forceinline__ uint packbf2(float lo, float hi) {
    return (uint)f2bf(lo) | ((uint)f2bf(hi) << 16);
}
// truncating pack: 2 VALU ops; P>=0 feeds a ratio -> bias cancels to ~0.2%
static __device__ __forceinline__ uint packtrunc(float lo, float hi) {
    uint l = __builtin_bit_cast(uint, lo);
    uint h = __builtin_bit_cast(uint, hi);
    return (l >> 16) | (h & 0xffff0000u);
}

// ---------------- Stage A: projections -> bf16 MFMA layouts ----------------
// grid (256, 6): y = proj*2 + half16 (R9 form: 3072 waves). theta pre-scaled.
__global__ __launch_bounds__(128) void proj_kernel(
    const float* __restrict__ x,
    const float* __restrict__ g_w, const float* __restrict__ g_b,
    const float* __restrict__ th_w, const float* __restrict__ th_b,
    const float* __restrict__ ph_w, const float* __restrict__ ph_b,
    ushort* __restrict__ gcn, ushort* __restrict__ tht, ushort* __restrict__ pht)
{
    int gy = blockIdx.y;
    int pj = gy >> 1, half = gy & 1;
    const float* wsrc = (pj == 0) ? g_w : (pj == 1) ? th_w : ph_w;
    const float* bsrc = (pj == 0) ? g_b : (pj == 1) ? th_b : ph_b;
    __shared__ float w[16][64];
    __shared__ float bias[16];
    int tid = threadIdx.x;
    for (int i = tid; i < 1024; i += 128) w[i >> 6][i & 63] = wsrc[half * 1024 + i];
    if (tid < 16) bias[tid] = bsrc[half * 16 + tid];
    __syncthreads();

    int ng = blockIdx.x * 128 + tid;
    int b = ng >> 12, n = ng & 4095;
    const float* xb = x + (size_t)b * C_IN * N_POS + n;
    float xr[64];
    #pragma unroll
    for (int c = 0; c < 64; c++) xr[c] = xb[(size_t)c * N_POS];

    float acc[16];
    #pragma unroll
    for (int o = 0; o < 16; o++) {
        float a = bias[o];
        const float4* w4 = (const float4*)w[o];
        #pragma unroll
        for (int c4 = 0; c4 < 16; c4++) {
            float4 wv = w4[c4];
            a += wv.x * xr[c4*4+0] + wv.y * xr[c4*4+1]
               + wv.z * xr[c4*4+2] + wv.w * xr[c4*4+3];
        }
        if (pj == 1) a *= L2E;
        acc[o] = a;
    }

    if (pj == 0) {
        #pragma unroll
        for (int c = 0; c < 16; c++)
            gcn[((size_t)(b * IC + half * 16 + c)) * N_POS + n] = f2bf(acc[c]);
    } else {
        ushort* dst = ((pj == 1) ? tht : pht) + ((size_t)(b * N_POS + n)) * IC + half * 16;
        uint4v pk0, pk1;
        #pragma unroll
        for (int i = 0; i < 4; i++) pk0[i] = packbf2(acc[2*i], acc[2*i+1]);
        #pragma unroll
        for (int i = 0; i < 4; i++) pk1[i] = packbf2(acc[8+2*i], acc[8+2*i+1]);
        *(uint4v*)dst = pk0;
        *(uint4v*)(dst + 8) = pk1;
    }
}

// -------- mb prep: keys (mbt) pre-scaled by 32^-0.5 * log2e ----------------
__global__ __launch_bounds__(256) void mbprep_kernel(
    const float* __restrict__ mb, ushort* __restrict__ mbt,
    ushort* __restrict__ mbb)
{
    int i = blockIdx.x * 256 + threadIdx.x;   // 8192
    int c = i >> 8, k = i & 255;
    float v = mb[i];
    mbb[i] = f2bf(v);
    mbt[k * 32 + c] = f2bf(v * (0.17677669529663687f * L2E));
}

// ------------- Stage B: non-local attention (unchanged from R10) ------------
__global__ __launch_bounds__(256) void attn_kernel(
    const ushort* __restrict__ tht, const ushort* __restrict__ pht,
    const ushort* __restrict__ gcn, float* __restrict__ yp,
    float* __restrict__ dnm)
{
    __shared__ float redY[4][2][32][32];   // 32 KB
    __shared__ float redD[4][2][32];
    int tid = threadIdx.x;
    int s = tid >> 6, lane = tid & 63;
    int bid = blockIdx.x;
    int b = bid & 7;                 // batch -> XCD locality
    int rest = bid >> 3;             // 0..127
    int qp = rest >> 1;              // 0..63
    int half = rest & 1;
    int q0 = qp * 64;
    int mbase = (half * 4 + s) * 512;
    int cl = lane & 31, h = lane >> 5;
    int t4 = (cl >> 2) & 3;
    int pcl = (t4 == 1 || t4 == 2) ? (cl ^ 12) : cl;   // pi row permutation

    const ushort* thpA = tht + ((size_t)(b * N_POS + q0 + cl)) * IC + 8 * h;
    bf16x8 thA0 = *(const bf16x8*)thpA;
    bf16x8 thA1 = *(const bf16x8*)(thpA + 16);
    const ushort* thpB = thpA + 32 * IC;
    bf16x8 thB0 = *(const bf16x8*)thpB;
    bf16x8 thB1 = *(const bf16x8*)(thpB + 16);

    const ushort* phbase = pht + (size_t)b * N_POS * IC;
    const ushort* gbase  = gcn + ((size_t)(b * IC + cl)) * N_POS;

    f32x16 yA0, yA1, yB0, yB1, zero;
    #pragma unroll
    for (int i = 0; i < 16; i++) {
        yA0[i] = 0.f; yA1[i] = 0.f; yB0[i] = 0.f; yB1[i] = 0.f; zero[i] = 0.f;
    }
    float sumeA = 0.f, sumeB = 0.f;

    #pragma unroll 2
    for (int mt = 0; mt < 16; ++mt) {
        int m0 = mbase + mt * 32;
        const ushort* php = phbase + ((size_t)(m0 + pcl)) * IC + 8 * h;
        bf16x8 ph0 = *(const bf16x8*)php;
        bf16x8 ph1 = *(const bf16x8*)(php + 16);
        const ushort* gp = gbase + m0 + 8 * h;
        bf16x8 g0 = *(const bf16x8*)gp;
        bf16x8 g1 = *(const bf16x8*)(gp + 16);

        f32x16 sv = __builtin_amdgcn_mfma_f32_32x32x16_bf16(ph0, thA0, zero, 0, 0, 0);
        sv = __builtin_amdgcn_mfma_f32_32x32x16_bf16(ph1, thA1, sv, 0, 0, 0);
        uint wA[8];
        #pragma unroll
        for (int i = 0; i < 8; i++) {
            float p0 = __builtin_amdgcn_exp2f(sv[2*i]);
            float p1 = __builtin_amdgcn_exp2f(sv[2*i+1]);
            sumeA += p0 + p1;
            wA[i] = packtrunc(p0, p1);
        }
        f32x16 sw = __builtin_amdgcn_mfma_f32_32x32x16_bf16(ph0, thB0, zero, 0, 0, 0);
        sw = __builtin_amdgcn_mfma_f32_32x32x16_bf16(ph1, thB1, sw, 0, 0, 0);
        uint wB[8];
        #pragma unroll
        for (int i = 0; i < 8; i++) {
            float p0 = __builtin_amdgcn_exp2f(sw[2*i]);
            float p1 = __builtin_amdgcn_exp2f(sw[2*i+1]);
            sumeB += p0 + p1;
            wB[i] = packtrunc(p0, p1);
        }

        uint4v aA0, aA1, aB0, aB1;
        aA0[0] = wA[0]; aA0[1] = wA[1]; aA0[2] = wA[2]; aA0[3] = wA[3];
        aA1[0] = wA[4]; aA1[1] = wA[5]; aA1[2] = wA[6]; aA1[3] = wA[7];
        aB0[0] = wB[0]; aB0[1] = wB[1]; aB0[2] = wB[2]; aB0[3] = wB[3];
        aB1[0] = wB[4]; aB1[1] = wB[5]; aB1[2] = wB[6]; aB1[3] = wB[7];

        yA0 = __builtin_amdgcn_mfma_f32_32x32x16_bf16(
            __builtin_bit_cast(bf16x8, aA0), g0, yA0, 0, 0, 0);
        yA1 = __builtin_amdgcn_mfma_f32_32x32x16_bf16(
            __builtin_bit_cast(bf16x8, aA1), g1, yA1, 0, 0, 0);
        yB0 = __builtin_amdgcn_mfma_f32_32x32x16_bf16(
            __builtin_bit_cast(bf16x8, aB0), g0, yB0, 0, 0, 0);
        yB1 = __builtin_amdgcn_mfma_f32_32x32x16_bf16(
            __builtin_bit_cast(bf16x8, aB1), g1, yB1, 0, 0, 0);
    }

    sumeA += __shfl_xor(sumeA, 32);
    sumeB += __shfl_xor(sumeB, 32);
    if (lane < 32) { redD[s][0][cl] = sumeA; redD[s][1][cl] = sumeB; }
    #pragma unroll
    for (int r = 0; r < 16; r++) {
        int q = (r & 3) + 8 * (r >> 2) + 4 * h;
        redY[s][0][q][cl] = yA0[r] + yA1[r];
        redY[s][1][q][cl] = yB0[r] + yB1[r];
    }
    __syncthreads();

    int q = tid >> 3, c4 = tid & 7;
    #pragma unroll
    for (int j = 0; j < 2; j++) {
        float den = redD[0][j][q] + redD[1][j][q] + redD[2][j][q] + redD[3][j][q];
        float4 v0 = *(const float4*)&redY[0][j][q][c4 * 4];
        float4 v1 = *(const float4*)&redY[1][j][q][c4 * 4];
        float4 v2 = *(const float4*)&redY[2][j][q][c4 * 4];
        float4 v3 = *(const float4*)&redY[3][j][q][c4 * 4];
        float4 vv;
        vv.x = v0.x + v1.x + v2.x + v3.x;
        vv.y = v0.y + v1.y + v2.y + v3.y;
        vv.z = v0.z + v1.z + v2.z + v3.z;
        vv.w = v0.w + v1.w + v2.w + v3.w;
        size_t t = ((size_t)(b * 128 + qp * 2 + j)) * 2 + half;
        *(float4*)(yp + t * 1024 + q * 32 + c4 * 4) = vv;
        if (c4 == 0) dnm[t * 32 + q] = den;
    }
}

// ---- Stage C+D fused: mb attention (per wave) -> LDS, then out matmul ------
// grid 256 blocks x 256 thr: block = (b, 128-n group); wave s = one 32-q tile.
__global__ __launch_bounds__(256) void mbout_kernel(
    const ushort* __restrict__ pht, const ushort* __restrict__ mbt,
    const ushort* __restrict__ mbb, const float* __restrict__ yp,
    const float* __restrict__ dnm, const float* __restrict__ x,
    const float* __restrict__ Ww, const float* __restrict__ Wb,
    const float* __restrict__ Wzw, const float* __restrict__ Wzb,
    float* __restrict__ out)
{
    __shared__ float sW[64][32], sWz[64][32];
    __shared__ float sb[64];
    __shared__ float ly1[128][33];     // +1 pad: phase-2 rows hit distinct banks
    int tid = threadIdx.x;
    int bid = blockIdx.x;
    int b = bid & 7, grp = bid >> 3;   // batch -> XCD locality
    int n0 = grp * 128;

    for (int i = tid; i < 2048; i += 256) {
        int o = i >> 5, c = i & 31;
        sW[o][c]  = Ww[i];
        sWz[o][c] = Wzw[i];
    }
    if (tid < 64) sb[tid] = Wb[tid] + Wzb[tid];

    // ---- wave phase: mb attention for q-tile q0 = n0 + s*32 ----
    int s = tid >> 6, lane = tid & 63;
    int cl = lane & 31, h = lane >> 5;
    int t4 = (cl >> 2) & 3;
    int pcl = (t4 == 1 || t4 == 2) ? (cl ^ 12) : cl;
    int q0 = n0 + s * 32;

    const ushort* php = pht + ((size_t)(b * N_POS + q0 + cl)) * IC + 8 * h;
    bf16x8 qf0 = *(const bf16x8*)php;
    bf16x8 qf1 = *(const bf16x8*)(php + 16);

    f32x16 yaccA, yaccB, zero;
    #pragma unroll
    for (int i = 0; i < 16; i++) { yaccA[i] = 0.f; yaccB[i] = 0.f; zero[i] = 0.f; }
    float sume = 0.f;

    #pragma unroll 2
    for (int kt = 0; kt < 8; ++kt) {
        int k0 = kt * 32;
        const ushort* ap = mbt + ((size_t)(k0 + pcl)) * IC + 8 * h;
        bf16x8 af0 = *(const bf16x8*)ap;
        bf16x8 af1 = *(const bf16x8*)(ap + 16);
        const ushort* bp = mbb + (size_t)cl * 256 + k0 + 8 * h;
        bf16x8 bf0 = *(const bf16x8*)bp;
        bf16x8 bf1 = *(const bf16x8*)(bp + 16);

        f32x16 sv = __builtin_amdgcn_mfma_f32_32x32x16_bf16(af0, qf0, zero, 0, 0, 0);
        sv = __builtin_amdgcn_mfma_f32_32x32x16_bf16(af1, qf1, sv, 0, 0, 0);

        uint w[8];
        #pragma unroll
        for (int i = 0; i < 8; i++) {
            float p0 = __builtin_amdgcn_exp2f(sv[2*i]);
            float p1 = __builtin_amdgcn_exp2f(sv[2*i+1]);
            sume += p0 + p1;
            w[i] = packtrunc(p0, p1);
        }
        uint4v a0, a1;
        a0[0] = w[0]; a0[1] = w[1]; a0[2] = w[2]; a0[3] = w[3];
        a1[0] = w[4]; a1[1] = w[5]; a1[2] = w[6]; a1[3] = w[7];

        yaccA = __builtin_amdgcn_mfma_f32_32x32x16_bf16(
            __builtin_bit_cast(bf16x8, a0), bf0, yaccA, 0, 0, 0);
        yaccB = __builtin_amdgcn_mfma_f32_32x32x16_bf16(
            __builtin_bit_cast(bf16x8, a1), bf1, yaccB, 0, 0, 0);
    }

    sume += __shfl_xor(sume, 32);          // lane q (0..31) holds denom[q]
    #pragma unroll
    for (int r = 0; r < 16; r++) {
        int q = (r & 3) + 8 * (r >> 2) + 4 * h;
        float d = __shfl(sume, q);
        ly1[s * 32 + q][cl] = (yaccA[r] + yaccB[r]) / d;
    }
    __syncthreads();

    // ---- out phase: thread = (nl, oh); 32 outputs each ----
    int nl = tid >> 1, oh = tid & 1;
    int n = n0 + nl;
    int qt = n >> 5, q = n & 31;
    size_t t0 = ((size_t)(b * 128 + qt)) * 2;
    float inv = 1.f / (dnm[t0 * 32 + q] + dnm[t0 * 32 + 32 + q]);

    const float* yp0 = yp + t0 * 1024 + q * 32;
    const float* yp1 = yp0 + 1024;
    float yv[32], y1v[32];
    #pragma unroll
    for (int c4 = 0; c4 < 8; c4++) {
        float4 v0 = ((const float4*)yp0)[c4];
        float4 v1 = ((const float4*)yp1)[c4];
        yv[c4*4+0] = (v0.x + v1.x) * inv;
        yv[c4*4+1] = (v0.y + v1.y) * inv;
        yv[c4*4+2] = (v0.z + v1.z) * inv;
        yv[c4*4+3] = (v0.w + v1.w) * inv;
    }
    #pragma unroll
    for (int c = 0; c < 32; c++) y1v[c] = ly1[nl][c];

    const float* xb = x   + ((size_t)(b * C_IN + oh * 32)) * N_POS + n;
    float*       ob = out + ((size_t)(b * C_IN + oh * 32)) * N_POS + n;
    for (int o = 0; o < 32; o++) {
        float acc = sb[oh * 32 + o] + xb[(size_t)o * N_POS];
        const float4* w4  = (const float4*)sW[oh * 32 + o];
        const float4* wz4 = (const float4*)sWz[oh * 32 + o];
        #pragma unroll
        for (int c4 = 0; c4 < 8; c4++) {
            float4 a = w4[c4], z = wz4[c4];
            acc += a.x * yv[c4*4+0] + a.y * yv[c4*4+1] + a.z * yv[c4*4+2] + a.w * yv[c4*4+3];
            acc += z.x * y1v[c4*4+0] + z.y * y1v[c4*4+1] + z.z * y1v[c4*4+2] + z.w * y1v[c4*4+3];
        }
        ob[(size_t)o * N_POS] = acc;
    }
}

extern "C" void kernel_launch(void* const* d_in, const int* in_sizes, int n_in,
                              void* d_out, int out_size, void* d_ws, size_t ws_size,
                              hipStream_t stream) {
    const float* x    = (const float*)d_in[0];
    const float* g_w  = (const float*)d_in[1];
    const float* g_b  = (const float*)d_in[2];
    const float* th_w = (const float*)d_in[3];
    const float* th_b = (const float*)d_in[4];
    const float* ph_w = (const float*)d_in[5];
    const float* ph_b = (const float*)d_in[6];
    const float* W_w  = (const float*)d_in[7];
    const float* W_b  = (const float*)d_in[8];
    const float* Wz_w = (const float*)d_in[9];
    const float* Wz_b = (const float*)d_in[10];
    const float* mb   = (const float*)d_in[11];
    float* out = (float*)d_out;

    char* w = (char*)d_ws;
    ushort* tht = (ushort*)w;                        // 2 MB
    ushort* pht = (ushort*)(w + (2u << 20));         // 2 MB
    ushort* gcn = (ushort*)(w + (4u << 20));         // 2 MB
    ushort* mbt = (ushort*)(w + (6u << 20));         // 16 KB
    ushort* mbb = (ushort*)(w + (6u << 20) + 16384); // 16 KB
    float*  yp  = (float*)(w + (9u << 20));          // 8 MB  [b*128+qt][2][1024]
    float*  dnm = (float*)(w + (17u << 20));         // 256 KB

    proj_kernel<<<dim3(256, 6), 128, 0, stream>>>(x, g_w, g_b, th_w, th_b,
                                                  ph_w, ph_b, gcn, tht, pht);
    mbprep_kernel<<<32, 256, 0, stream>>>(mb, mbt, mbb);
    attn_kernel<<<1024, 256, 0, stream>>>(tht, pht, gcn, yp, dnm);
    mbout_kernel<<<256, 256, 0, stream>>>(pht, mbt, mbb, yp, dnm, x,
                                          W_w, W_b, Wz_w, Wz_b, out);
}

// Round 12
// 78.067 us; speedup vs baseline: 1.2881x; 1.1367x over previous
//
#include <hip/hip_runtime.h>
#include <hip/hip_bf16.h>

#define N_POS 4096
#define C_IN 64
#define IC 32
#define L2E 1.4426950408889634f

typedef float f32x16 __attribute__((ext_vector_type(16)));
typedef short bf16x8 __attribute__((ext_vector_type(8)));
typedef unsigned int uint;
typedef uint uint4v __attribute__((ext_vector_type(4)));
typedef unsigned short ushort;

static __device__ __forceinline__ ushort f2bf(float f) {
    __hip_bfloat16 h = __float2bfloat16(f);
    return __builtin_bit_cast(ushort, h);
}
static __device__ __forceinline__ float bf2f(ushort u) {
    uint v = ((uint)u) << 16;
    return __builtin_bit_cast(float, v);
}
static __device__ __forceinline__ uint packbf2(float lo, float hi) {
    return (uint)f2bf(lo) | ((uint)f2bf(hi) << 16);
}
// truncating pack in ONE v_perm_b32: D = [hi.b3, hi.b2, lo.b3, lo.b2]
static __device__ __forceinline__ uint packtrunc(float lo, float hi) {
    return __builtin_amdgcn_perm(__builtin_bit_cast(uint, hi),
                                 __builtin_bit_cast(uint, lo), 0x07060302u);
}

// ---------------- Stage A: projections -> bf16 MFMA layouts ----------------
// grid (256, 6): y = proj*2 + half16. theta pre-scaled by log2(e).
// gy==0 blocks 0..63 also handle mb prep (folded kernel).
__global__ __launch_bounds__(128) void proj_kernel(
    const float* __restrict__ x,
    const float* __restrict__ g_w, const float* __restrict__ g_b,
    const float* __restrict__ th_w, const float* __restrict__ th_b,
    const float* __restrict__ ph_w, const float* __restrict__ ph_b,
    const float* __restrict__ mb,
    ushort* __restrict__ gcn, ushort* __restrict__ tht, ushort* __restrict__ pht,
    ushort* __restrict__ mbt, ushort* __restrict__ mbb)
{
    int gy = blockIdx.y;
    int pj = gy >> 1, half = gy & 1;
    const float* wsrc = (pj == 0) ? g_w : (pj == 1) ? th_w : ph_w;
    const float* bsrc = (pj == 0) ? g_b : (pj == 1) ? th_b : ph_b;
    __shared__ float w[16][64];
    __shared__ float bias[16];
    int tid = threadIdx.x;
    for (int i = tid; i < 1024; i += 128) w[i >> 6][i & 63] = wsrc[half * 1024 + i];
    if (tid < 16) bias[tid] = bsrc[half * 16 + tid];
    __syncthreads();

    int ng = blockIdx.x * 128 + tid;
    int b = ng >> 12, n = ng & 4095;
    const float* xb = x + (size_t)b * C_IN * N_POS + n;
    float xr[64];
    #pragma unroll
    for (int c = 0; c < 64; c++) xr[c] = xb[(size_t)c * N_POS];

    float acc[16];
    #pragma unroll
    for (int o = 0; o < 16; o++) {
        float a = bias[o];
        const float4* w4 = (const float4*)w[o];
        #pragma unroll
        for (int c4 = 0; c4 < 16; c4++) {
            float4 wv = w4[c4];
            a += wv.x * xr[c4*4+0] + wv.y * xr[c4*4+1]
               + wv.z * xr[c4*4+2] + wv.w * xr[c4*4+3];
        }
        if (pj == 1) a *= L2E;
        acc[o] = a;
    }

    if (pj == 0) {
        #pragma unroll
        for (int c = 0; c < 16; c++)
            gcn[((size_t)(b * IC + half * 16 + c)) * N_POS + n] = f2bf(acc[c]);
    } else {
        ushort* dst = ((pj == 1) ? tht : pht) + ((size_t)(b * N_POS + n)) * IC + half * 16;
        uint4v pk0, pk1;
        #pragma unroll
        for (int i = 0; i < 4; i++) pk0[i] = packbf2(acc[2*i], acc[2*i+1]);
        #pragma unroll
        for (int i = 0; i < 4; i++) pk1[i] = packbf2(acc[8+2*i], acc[8+2*i+1]);
        *(uint4v*)dst = pk0;
        *(uint4v*)(dst + 8) = pk1;
    }

    // folded mb prep: 64 blocks x 128 thr = 8192 elements
    if (gy == 0 && blockIdx.x < 64) {
        int i = blockIdx.x * 128 + tid;
        int c = i >> 8, k = i & 255;
        float v = mb[i];
        mbb[i] = f2bf(v);
        mbt[k * 32 + c] = f2bf(v * (0.17677669529663687f * L2E));
    }
}

// ------------- Stage B: non-local attention (R11 + v_perm pack) -------------
__global__ __launch_bounds__(256) void attn_kernel(
    const ushort* __restrict__ tht, const ushort* __restrict__ pht,
    const ushort* __restrict__ gcn, float* __restrict__ yp,
    float* __restrict__ dnm)
{
    __shared__ float redY[4][2][32][32];   // 32 KB
    __shared__ float redD[4][2][32];
    int tid = threadIdx.x;
    int s = tid >> 6, lane = tid & 63;
    int bid = blockIdx.x;
    int b = bid & 7;                 // batch -> XCD locality
    int rest = bid >> 3;             // 0..127
    int qp = rest >> 1;              // 0..63
    int half = rest & 1;
    int q0 = qp * 64;
    int mbase = (half * 4 + s) * 512;
    int cl = lane & 31, h = lane >> 5;
    int t4 = (cl >> 2) & 3;
    int pcl = (t4 == 1 || t4 == 2) ? (cl ^ 12) : cl;   // pi row permutation

    const ushort* thpA = tht + ((size_t)(b * N_POS + q0 + cl)) * IC + 8 * h;
    bf16x8 thA0 = *(const bf16x8*)thpA;
    bf16x8 thA1 = *(const bf16x8*)(thpA + 16);
    const ushort* thpB = thpA + 32 * IC;
    bf16x8 thB0 = *(const bf16x8*)thpB;
    bf16x8 thB1 = *(const bf16x8*)(thpB + 16);

    const ushort* phbase = pht + (size_t)b * N_POS * IC;
    const ushort* gbase  = gcn + ((size_t)(b * IC + cl)) * N_POS;

    f32x16 yA0, yA1, yB0, yB1, zero;
    #pragma unroll
    for (int i = 0; i < 16; i++) {
        yA0[i] = 0.f; yA1[i] = 0.f; yB0[i] = 0.f; yB1[i] = 0.f; zero[i] = 0.f;
    }
    float sumeA = 0.f, sumeB = 0.f;

    #pragma unroll 2
    for (int mt = 0; mt < 16; ++mt) {
        int m0 = mbase + mt * 32;
        const ushort* php = phbase + ((size_t)(m0 + pcl)) * IC + 8 * h;
        bf16x8 ph0 = *(const bf16x8*)php;
        bf16x8 ph1 = *(const bf16x8*)(php + 16);
        const ushort* gp = gbase + m0 + 8 * h;
        bf16x8 g0 = *(const bf16x8*)gp;
        bf16x8 g1 = *(const bf16x8*)(gp + 16);

        f32x16 sv = __builtin_amdgcn_mfma_f32_32x32x16_bf16(ph0, thA0, zero, 0, 0, 0);
        sv = __builtin_amdgcn_mfma_f32_32x32x16_bf16(ph1, thA1, sv, 0, 0, 0);
        uint wA[8];
        #pragma unroll
        for (int i = 0; i < 8; i++) {
            float p0 = __builtin_amdgcn_exp2f(sv[2*i]);
            float p1 = __builtin_amdgcn_exp2f(sv[2*i+1]);
            sumeA += p0 + p1;
            wA[i] = packtrunc(p0, p1);
        }
        f32x16 sw = __builtin_amdgcn_mfma_f32_32x32x16_bf16(ph0, thB0, zero, 0, 0, 0);
        sw = __builtin_amdgcn_mfma_f32_32x32x16_bf16(ph1, thB1, sw, 0, 0, 0);
        uint wB[8];
        #pragma unroll
        for (int i = 0; i < 8; i++) {
            float p0 = __builtin_amdgcn_exp2f(sw[2*i]);
            float p1 = __builtin_amdgcn_exp2f(sw[2*i+1]);
            sumeB += p0 + p1;
            wB[i] = packtrunc(p0, p1);
        }

        uint4v aA0, aA1, aB0, aB1;
        aA0[0] = wA[0]; aA0[1] = wA[1]; aA0[2] = wA[2]; aA0[3] = wA[3];
        aA1[0] = wA[4]; aA1[1] = wA[5]; aA1[2] = wA[6]; aA1[3] = wA[7];
        aB0[0] = wB[0]; aB0[1] = wB[1]; aB0[2] = wB[2]; aB0[3] = wB[3];
        aB1[0] = wB[4]; aB1[1] = wB[5]; aB1[2] = wB[6]; aB1[3] = wB[7];

        yA0 = __builtin_amdgcn_mfma_f32_32x32x16_bf16(
            __builtin_bit_cast(bf16x8, aA0), g0, yA0, 0, 0, 0);
        yA1 = __builtin_amdgcn_mfma_f32_32x32x16_bf16(
            __builtin_bit_cast(bf16x8, aA1), g1, yA1, 0, 0, 0);
        yB0 = __builtin_amdgcn_mfma_f32_32x32x16_bf16(
            __builtin_bit_cast(bf16x8, aB0), g0, yB0, 0, 0, 0);
        yB1 = __builtin_amdgcn_mfma_f32_32x32x16_bf16(
            __builtin_bit_cast(bf16x8, aB1), g1, yB1, 0, 0, 0);
    }

    sumeA += __shfl_xor(sumeA, 32);
    sumeB += __shfl_xor(sumeB, 32);
    if (lane < 32) { redD[s][0][cl] = sumeA; redD[s][1][cl] = sumeB; }
    #pragma unroll
    for (int r = 0; r < 16; r++) {
        int q = (r & 3) + 8 * (r >> 2) + 4 * h;
        redY[s][0][q][cl] = yA0[r] + yA1[r];
        redY[s][1][q][cl] = yB0[r] + yB1[r];
    }
    __syncthreads();

    int q = tid >> 3, c4 = tid & 7;
    #pragma unroll
    for (int j = 0; j < 2; j++) {
        float den = redD[0][j][q] + redD[1][j][q] + redD[2][j][q] + redD[3][j][q];
        float4 v0 = *(const float4*)&redY[0][j][q][c4 * 4];
        float4 v1 = *(const float4*)&redY[1][j][q][c4 * 4];
        float4 v2 = *(const float4*)&redY[2][j][q][c4 * 4];
        float4 v3 = *(const float4*)&redY[3][j][q][c4 * 4];
        float4 vv;
        vv.x = v0.x + v1.x + v2.x + v3.x;
        vv.y = v0.y + v1.y + v2.y + v3.y;
        vv.z = v0.z + v1.z + v2.z + v3.z;
        vv.w = v0.w + v1.w + v2.w + v3.w;
        size_t t = ((size_t)(b * 128 + qp * 2 + j)) * 2 + half;
        *(float4*)(yp + t * 1024 + q * 32 + c4 * 4) = vv;
        if (c4 == 0) dnm[t * 32 + q] = den;
    }
}

// ---- Stage C+D fused: 512 blocks, all-wave mb phase + balanced out phase ---
// block = (b, 64-n group). Phase 1: wave s -> q-tile j=s&1, k-half kh=s>>1.
// Phase 2: wave s -> 16-output slice, lane -> n (coalesced x/out).
__global__ __launch_bounds__(256) void mbout_kernel(
    const ushort* __restrict__ pht, const ushort* __restrict__ mbt,
    const ushort* __restrict__ mbb, const float* __restrict__ yp,
    const float* __restrict__ dnm, const float* __restrict__ x,
    const float* __restrict__ Ww, const float* __restrict__ Wb,
    const float* __restrict__ Wzw, const float* __restrict__ Wzb,
    float* __restrict__ out)
{
    __shared__ float sW[64][32], sWz[64][32];
    __shared__ float sb[64];
    __shared__ float ly1p[4][32][36];   // wave partials, 16B-aligned rows
    __shared__ float sumeL[4][32];
    int tid = threadIdx.x;
    int bid = blockIdx.x;
    int b = bid & 7, grp = bid >> 3;    // batch -> XCD locality; grp 0..63
    int n0 = grp * 64;

    for (int i = tid; i < 2048; i += 256) {
        sW[i >> 5][i & 31]  = Ww[i];
        sWz[i >> 5][i & 31] = Wzw[i];
    }
    if (tid < 64) sb[tid] = Wb[tid] + Wzb[tid];

    // ---- phase 1: mb attention, k-split across wave pairs ----
    int s = tid >> 6, lane = tid & 63;
    int j = s & 1, kh = s >> 1;
    int q0 = n0 + j * 32;
    int cl = lane & 31, h = lane >> 5;
    int t4 = (cl >> 2) & 3;
    int pcl = (t4 == 1 || t4 == 2) ? (cl ^ 12) : cl;

    const ushort* php = pht + ((size_t)(b * N_POS + q0 + cl)) * IC + 8 * h;
    bf16x8 qf0 = *(const bf16x8*)php;
    bf16x8 qf1 = *(const bf16x8*)(php + 16);

    f32x16 yaccA, yaccB, zero;
    #pragma unroll
    for (int i = 0; i < 16; i++) { yaccA[i] = 0.f; yaccB[i] = 0.f; zero[i] = 0.f; }
    float sume = 0.f;

    #pragma unroll
    for (int kt = 0; kt < 4; ++kt) {
        int k0 = (kh * 4 + kt) * 32;
        const ushort* ap = mbt + ((size_t)(k0 + pcl)) * IC + 8 * h;
        bf16x8 af0 = *(const bf16x8*)ap;
        bf16x8 af1 = *(const bf16x8*)(ap + 16);
        const ushort* bp = mbb + (size_t)cl * 256 + k0 + 8 * h;
        bf16x8 bf0 = *(const bf16x8*)bp;
        bf16x8 bf1 = *(const bf16x8*)(bp + 16);

        f32x16 sv = __builtin_amdgcn_mfma_f32_32x32x16_bf16(af0, qf0, zero, 0, 0, 0);
        sv = __builtin_amdgcn_mfma_f32_32x32x16_bf16(af1, qf1, sv, 0, 0, 0);

        uint w[8];
        #pragma unroll
        for (int i = 0; i < 8; i++) {
            float p0 = __builtin_amdgcn_exp2f(sv[2*i]);
            float p1 = __builtin_amdgcn_exp2f(sv[2*i+1]);
            sume += p0 + p1;
            w[i] = packtrunc(p0, p1);
        }
        uint4v a0, a1;
        a0[0] = w[0]; a0[1] = w[1]; a0[2] = w[2]; a0[3] = w[3];
        a1[0] = w[4]; a1[1] = w[5]; a1[2] = w[6]; a1[3] = w[7];

        yaccA = __builtin_amdgcn_mfma_f32_32x32x16_bf16(
            __builtin_bit_cast(bf16x8, a0), bf0, yaccA, 0, 0, 0);
        yaccB = __builtin_amdgcn_mfma_f32_32x32x16_bf16(
            __builtin_bit_cast(bf16x8, a1), bf1, yaccB, 0, 0, 0);
    }

    sume += __shfl_xor(sume, 32);          // lane q (0..31) holds partial denom
    if (lane < 32) sumeL[s][cl] = sume;
    #pragma unroll
    for (int r = 0; r < 16; r++) {
        int q = (r & 3) + 8 * (r >> 2) + 4 * h;
        ly1p[s][q][cl] = yaccA[r] + yaccB[r];
    }
    __syncthreads();

    // ---- phase 2: wave s -> outputs [obase, obase+16), lane -> n ----
    int obase = (s & 1) * 32 + (s >> 1) * 16;
    int n = n0 + lane;
    int jj = lane >> 5, q = lane & 31;

    float inv1 = 1.f / (sumeL[jj][q] + sumeL[2 + jj][q]);
    float y1v[32];
    #pragma unroll
    for (int c4 = 0; c4 < 8; c4++) {
        float4 p0 = *(const float4*)&ly1p[jj][q][c4 * 4];
        float4 p1 = *(const float4*)&ly1p[2 + jj][q][c4 * 4];
        y1v[c4*4+0] = (p0.x + p1.x) * inv1;
        y1v[c4*4+1] = (p0.y + p1.y) * inv1;
        y1v[c4*4+2] = (p0.z + p1.z) * inv1;
        y1v[c4*4+3] = (p0.w + p1.w) * inv1;
    }

    int qt = n >> 5;
    size_t t0 = ((size_t)(b * 128 + qt)) * 2;
    float inv = 1.f / (dnm[t0 * 32 + q] + dnm[t0 * 32 + 32 + q]);
    const float* yp0 = yp + t0 * 1024 + q * 32;
    const float* yp1 = yp0 + 1024;
    float yv[32];
    #pragma unroll
    for (int c4 = 0; c4 < 8; c4++) {
        float4 v0 = ((const float4*)yp0)[c4];
        float4 v1 = ((const float4*)yp1)[c4];
        yv[c4*4+0] = (v0.x + v1.x) * inv;
        yv[c4*4+1] = (v0.y + v1.y) * inv;
        yv[c4*4+2] = (v0.z + v1.z) * inv;
        yv[c4*4+3] = (v0.w + v1.w) * inv;
    }

    const float* xb = x   + ((size_t)(b * C_IN + obase)) * N_POS + n;
    float*       ob = out + ((size_t)(b * C_IN + obase)) * N_POS + n;
    for (int o = 0; o < 16; o++) {
        float acc = sb[obase + o] + xb[(size_t)o * N_POS];
        const float4* w4  = (const float4*)sW[obase + o];
        const float4* wz4 = (const float4*)sWz[obase + o];
        #pragma unroll
        for (int c4 = 0; c4 < 8; c4++) {
            float4 a = w4[c4], z = wz4[c4];
            acc += a.x * yv[c4*4+0] + a.y * yv[c4*4+1] + a.z * yv[c4*4+2] + a.w * yv[c4*4+3];
            acc += z.x * y1v[c4*4+0] + z.y * y1v[c4*4+1] + z.z * y1v[c4*4+2] + z.w * y1v[c4*4+3];
        }
        ob[(size_t)o * N_POS] = acc;
    }
}

extern "C" void kernel_launch(void* const* d_in, const int* in_sizes, int n_in,
                              void* d_out, int out_size, void* d_ws, size_t ws_size,
                              hipStream_t stream) {
    const float* x    = (const float*)d_in[0];
    const float* g_w  = (const float*)d_in[1];
    const float* g_b  = (const float*)d_in[2];
    const float* th_w = (const float*)d_in[3];
    const float* th_b = (const float*)d_in[4];
    const float* ph_w = (const float*)d_in[5];
    const float* ph_b = (const float*)d_in[6];
    const float* W_w  = (const float*)d_in[7];
    const float* W_b  = (const float*)d_in[8];
    const float* Wz_w = (const float*)d_in[9];
    const float* Wz_b = (const float*)d_in[10];
    const float* mb   = (const float*)d_in[11];
    float* out = (float*)d_out;

    char* w = (char*)d_ws;
    ushort* tht = (ushort*)w;                        // 2 MB
    ushort* pht = (ushort*)(w + (2u << 20));         // 2 MB
    ushort* gcn = (ushort*)(w + (4u << 20));         // 2 MB
    ushort* mbt = (ushort*)(w + (6u << 20));         // 16 KB
    ushort* mbb = (ushort*)(w + (6u << 20) + 16384); // 16 KB
    float*  yp  = (float*)(w + (9u << 20));          // 8 MB  [b*128+qt][2][1024]
    float*  dnm = (float*)(w + (17u << 20));         // 256 KB

    proj_kernel<<<dim3(256, 6), 128, 0, stream>>>(x, g_w, g_b, th_w, th_b,
                                                  ph_w, ph_b, mb,
                                                  gcn, tht, pht, mbt, mbb);
    attn_kernel<<<1024, 256, 0, stream>>>(tht, pht, gcn, yp, dnm);
    mbout_kernel<<<512, 256, 0, stream>>>(pht, mbt, mbb, yp, dnm, x,
                                          W_w, W_b, Wz_w, Wz_b, out);
}

// Round 13
// 74.309 us; speedup vs baseline: 1.3533x; 1.0506x over previous
//
#include <hip/hip_runtime.h>
#include <hip/hip_bf16.h>

#define N_POS 4096
#define C_IN 64
#define IC 32
#define L2E 1.4426950408889634f

typedef float f32x16 __attribute__((ext_vector_type(16)));
typedef short bf16x8 __attribute__((ext_vector_type(8)));
typedef unsigned int uint;
typedef uint uint4v __attribute__((ext_vector_type(4)));
typedef unsigned short ushort;

static __device__ __forceinline__ ushort f2bf(float f) {
    __hip_bfloat16 h = __float2bfloat16(f);
    return __builtin_bit_cast(ushort, h);
}
static __device__ __forceinline__ uint packbf2(float lo, float hi) {
    return (uint)f2bf(lo) | ((uint)f2bf(hi) << 16);
}
// truncating pack in ONE v_perm_b32: D = [hi.b3, hi.b2, lo.b3, lo.b2]
static __device__ __forceinline__ uint packtrunc(float lo, float hi) {
    return __builtin_amdgcn_perm(__builtin_bit_cast(uint, hi),
                                 __builtin_bit_cast(uint, lo), 0x07060302u);
}

// ---------------- Stage A: projections -> bf16 MFMA layouts ----------------
// grid (256, 6): y = proj*2 + half16. theta pre-scaled by log2(e).
// gy==0 blocks 0..63 also handle mb prep (folded).
__global__ __launch_bounds__(128) void proj_kernel(
    const float* __restrict__ x,
    const float* __restrict__ g_w, const float* __restrict__ g_b,
    const float* __restrict__ th_w, const float* __restrict__ th_b,
    const float* __restrict__ ph_w, const float* __restrict__ ph_b,
    const float* __restrict__ mb,
    ushort* __restrict__ gcn, ushort* __restrict__ tht, ushort* __restrict__ pht,
    ushort* __restrict__ mbt, ushort* __restrict__ mbb)
{
    int gy = blockIdx.y;
    int pj = gy >> 1, half = gy & 1;
    const float* wsrc = (pj == 0) ? g_w : (pj == 1) ? th_w : ph_w;
    const float* bsrc = (pj == 0) ? g_b : (pj == 1) ? th_b : ph_b;
    __shared__ float w[16][64];
    __shared__ float bias[16];
    int tid = threadIdx.x;
    for (int i = tid; i < 1024; i += 128) w[i >> 6][i & 63] = wsrc[half * 1024 + i];
    if (tid < 16) bias[tid] = bsrc[half * 16 + tid];
    __syncthreads();

    int ng = blockIdx.x * 128 + tid;
    int b = ng >> 12, n = ng & 4095;
    const float* xb = x + (size_t)b * C_IN * N_POS + n;
    float xr[64];
    #pragma unroll
    for (int c = 0; c < 64; c++) xr[c] = xb[(size_t)c * N_POS];

    float acc[16];
    #pragma unroll
    for (int o = 0; o < 16; o++) {
        float a = bias[o];
        const float4* w4 = (const float4*)w[o];
        #pragma unroll
        for (int c4 = 0; c4 < 16; c4++) {
            float4 wv = w4[c4];
            a += wv.x * xr[c4*4+0] + wv.y * xr[c4*4+1]
               + wv.z * xr[c4*4+2] + wv.w * xr[c4*4+3];
        }
        if (pj == 1) a *= L2E;
        acc[o] = a;
    }

    if (pj == 0) {
        #pragma unroll
        for (int c = 0; c < 16; c++)
            gcn[((size_t)(b * IC + half * 16 + c)) * N_POS + n] = f2bf(acc[c]);
    } else {
        ushort* dst = ((pj == 1) ? tht : pht) + ((size_t)(b * N_POS + n)) * IC + half * 16;
        uint4v pk0, pk1;
        #pragma unroll
        for (int i = 0; i < 4; i++) pk0[i] = packbf2(acc[2*i], acc[2*i+1]);
        #pragma unroll
        for (int i = 0; i < 4; i++) pk1[i] = packbf2(acc[8+2*i], acc[8+2*i+1]);
        *(uint4v*)dst = pk0;
        *(uint4v*)(dst + 8) = pk1;
    }

    if (gy == 0 && blockIdx.x < 64) {
        int i = blockIdx.x * 128 + tid;
        int c = i >> 8, k = i & 255;
        float v = mb[i];
        mbb[i] = f2bf(v);
        mbt[k * 32 + c] = f2bf(v * (0.17677669529663687f * L2E));
    }
}

// ---- Fused: non-local attn (8 waves x 512 keys) + mb attn + out matmul -----
// block = (b, qpair): 512 thr. W1: waves 0-3 write redY; W2: waves 4-7 add
// (one writer/slot) while waves 0-3 run mb attention; W3: out matmul.
__global__ __launch_bounds__(512) void attn_fused(
    const ushort* __restrict__ tht, const ushort* __restrict__ pht,
    const ushort* __restrict__ gcn, const ushort* __restrict__ mbt,
    const ushort* __restrict__ mbb, const float* __restrict__ x,
    const float* __restrict__ Ww, const float* __restrict__ Wb,
    const float* __restrict__ Wzw, const float* __restrict__ Wzb,
    float* __restrict__ out)
{
    __shared__ float redY[4][2][32][36];   // 36 KB, 144B rows (16B-aligned)
    __shared__ float redD[8][2][32];       // 2 KB
    __shared__ float ly1p[4][32][36];      // 18 KB
    __shared__ float sumeL[4][32];         // 0.5 KB

    int tid = threadIdx.x;
    int s = tid >> 6, lane = tid & 63;
    int bid = blockIdx.x;
    int b = bid & 7;                 // batch -> XCD locality
    int qp = bid >> 3;               // 0..63
    int q0 = qp * 64;
    int mbase = s * 512;
    int cl = lane & 31, h = lane >> 5;
    int t4 = (cl >> 2) & 3;
    int pcl = (t4 == 1 || t4 == 2) ? (cl ^ 12) : cl;   // pi row permutation

    const ushort* thpA = tht + ((size_t)(b * N_POS + q0 + cl)) * IC + 8 * h;
    bf16x8 thA0 = *(const bf16x8*)thpA;
    bf16x8 thA1 = *(const bf16x8*)(thpA + 16);
    const ushort* thpB = thpA + 32 * IC;
    bf16x8 thB0 = *(const bf16x8*)thpB;
    bf16x8 thB1 = *(const bf16x8*)(thpB + 16);

    const ushort* phbase = pht + (size_t)b * N_POS * IC;
    const ushort* gbase  = gcn + ((size_t)(b * IC + cl)) * N_POS;

    f32x16 yA0, yA1, yB0, yB1, zero;
    #pragma unroll
    for (int i = 0; i < 16; i++) {
        yA0[i] = 0.f; yA1[i] = 0.f; yB0[i] = 0.f; yB1[i] = 0.f; zero[i] = 0.f;
    }
    float sumeA = 0.f, sumeB = 0.f;

    #pragma unroll 2
    for (int mt = 0; mt < 16; ++mt) {
        int m0 = mbase + mt * 32;
        const ushort* php = phbase + ((size_t)(m0 + pcl)) * IC + 8 * h;
        bf16x8 ph0 = *(const bf16x8*)php;
        bf16x8 ph1 = *(const bf16x8*)(php + 16);
        const ushort* gp = gbase + m0 + 8 * h;
        bf16x8 g0 = *(const bf16x8*)gp;
        bf16x8 g1 = *(const bf16x8*)(gp + 16);

        f32x16 sv = __builtin_amdgcn_mfma_f32_32x32x16_bf16(ph0, thA0, zero, 0, 0, 0);
        sv = __builtin_amdgcn_mfma_f32_32x32x16_bf16(ph1, thA1, sv, 0, 0, 0);
        uint wA[8];
        #pragma unroll
        for (int i = 0; i < 8; i++) {
            float p0 = __builtin_amdgcn_exp2f(sv[2*i]);
            float p1 = __builtin_amdgcn_exp2f(sv[2*i+1]);
            sumeA += p0 + p1;
            wA[i] = packtrunc(p0, p1);
        }
        f32x16 sw = __builtin_amdgcn_mfma_f32_32x32x16_bf16(ph0, thB0, zero, 0, 0, 0);
        sw = __builtin_amdgcn_mfma_f32_32x32x16_bf16(ph1, thB1, sw, 0, 0, 0);
        uint wB[8];
        #pragma unroll
        for (int i = 0; i < 8; i++) {
            float p0 = __builtin_amdgcn_exp2f(sw[2*i]);
            float p1 = __builtin_amdgcn_exp2f(sw[2*i+1]);
            sumeB += p0 + p1;
            wB[i] = packtrunc(p0, p1);
        }

        uint4v aA0, aA1, aB0, aB1;
        aA0[0] = wA[0]; aA0[1] = wA[1]; aA0[2] = wA[2]; aA0[3] = wA[3];
        aA1[0] = wA[4]; aA1[1] = wA[5]; aA1[2] = wA[6]; aA1[3] = wA[7];
        aB0[0] = wB[0]; aB0[1] = wB[1]; aB0[2] = wB[2]; aB0[3] = wB[3];
        aB1[0] = wB[4]; aB1[1] = wB[5]; aB1[2] = wB[6]; aB1[3] = wB[7];

        yA0 = __builtin_amdgcn_mfma_f32_32x32x16_bf16(
            __builtin_bit_cast(bf16x8, aA0), g0, yA0, 0, 0, 0);
        yA1 = __builtin_amdgcn_mfma_f32_32x32x16_bf16(
            __builtin_bit_cast(bf16x8, aA1), g1, yA1, 0, 0, 0);
        yB0 = __builtin_amdgcn_mfma_f32_32x32x16_bf16(
            __builtin_bit_cast(bf16x8, aB0), g0, yB0, 0, 0, 0);
        yB1 = __builtin_amdgcn_mfma_f32_32x32x16_bf16(
            __builtin_bit_cast(bf16x8, aB1), g1, yB1, 0, 0, 0);
    }

    // W1: denominators (all waves); partial PV (waves 0-3 write)
    sumeA += __shfl_xor(sumeA, 32);
    sumeB += __shfl_xor(sumeB, 32);
    if (lane < 32) { redD[s][0][cl] = sumeA; redD[s][1][cl] = sumeB; }
    if (s < 4) {
        #pragma unroll
        for (int r = 0; r < 16; r++) {
            int q = (r & 3) + 8 * (r >> 2) + 4 * h;
            redY[s][0][q][cl] = yA0[r] + yA1[r];
            redY[s][1][q][cl] = yB0[r] + yB1[r];
        }
    }
    __syncthreads();

    // W2: waves 4-7 accumulate (single writer per slot); waves 0-3 do mb attn
    if (s >= 4) {
        int sl = s - 4;
        #pragma unroll
        for (int r = 0; r < 16; r++) {
            int q = (r & 3) + 8 * (r >> 2) + 4 * h;
            redY[sl][0][q][cl] += yA0[r] + yA1[r];
            redY[sl][1][q][cl] += yB0[r] + yB1[r];
        }
    } else {
        int j = s & 1, kh = s >> 1;
        int mq0 = q0 + j * 32;
        const ushort* php = pht + ((size_t)(b * N_POS + mq0 + cl)) * IC + 8 * h;
        bf16x8 qf0 = *(const bf16x8*)php;
        bf16x8 qf1 = *(const bf16x8*)(php + 16);

        f32x16 zA, zB;
        #pragma unroll
        for (int i = 0; i < 16; i++) { zA[i] = 0.f; zB[i] = 0.f; }
        float sume = 0.f;

        #pragma unroll
        for (int kt = 0; kt < 4; ++kt) {
            int k0 = (kh * 4 + kt) * 32;
            const ushort* ap = mbt + ((size_t)(k0 + pcl)) * IC + 8 * h;
            bf16x8 af0 = *(const bf16x8*)ap;
            bf16x8 af1 = *(const bf16x8*)(ap + 16);
            const ushort* bp = mbb + (size_t)cl * 256 + k0 + 8 * h;
            bf16x8 bf0 = *(const bf16x8*)bp;
            bf16x8 bf1 = *(const bf16x8*)(bp + 16);

            f32x16 sv = __builtin_amdgcn_mfma_f32_32x32x16_bf16(af0, qf0, zero, 0, 0, 0);
            sv = __builtin_amdgcn_mfma_f32_32x32x16_bf16(af1, qf1, sv, 0, 0, 0);

            uint w[8];
            #pragma unroll
            for (int i = 0; i < 8; i++) {
                float p0 = __builtin_amdgcn_exp2f(sv[2*i]);
                float p1 = __builtin_amdgcn_exp2f(sv[2*i+1]);
                sume += p0 + p1;
                w[i] = packtrunc(p0, p1);
            }
            uint4v a0, a1;
            a0[0] = w[0]; a0[1] = w[1]; a0[2] = w[2]; a0[3] = w[3];
            a1[0] = w[4]; a1[1] = w[5]; a1[2] = w[6]; a1[3] = w[7];

            zA = __builtin_amdgcn_mfma_f32_32x32x16_bf16(
                __builtin_bit_cast(bf16x8, a0), bf0, zA, 0, 0, 0);
            zB = __builtin_amdgcn_mfma_f32_32x32x16_bf16(
                __builtin_bit_cast(bf16x8, a1), bf1, zB, 0, 0, 0);
        }

        sume += __shfl_xor(sume, 32);
        if (lane < 32) sumeL[s][cl] = sume;
        #pragma unroll
        for (int r = 0; r < 16; r++) {
            int q = (r & 3) + 8 * (r >> 2) + 4 * h;
            ly1p[s][q][cl] = zA[r] + zB[r];
        }
    }
    __syncthreads();

    // W3: out matmul. thread = (og = wave, nl = lane); n coalesced.
    int nl = lane, og = s;
    int n = q0 + nl;
    int jo = nl >> 5, qo = nl & 31;

    float den = 0.f;
    #pragma unroll
    for (int s8 = 0; s8 < 8; s8++) den += redD[s8][jo][qo];
    float inv = 1.f / den;
    float inv1 = 1.f / (sumeL[jo][qo] + sumeL[2 + jo][qo]);

    float yv[32], y1v[32];
    #pragma unroll
    for (int c4 = 0; c4 < 8; c4++) {
        float4 v0 = *(const float4*)&redY[0][jo][qo][c4 * 4];
        float4 v1 = *(const float4*)&redY[1][jo][qo][c4 * 4];
        float4 v2 = *(const float4*)&redY[2][jo][qo][c4 * 4];
        float4 v3 = *(const float4*)&redY[3][jo][qo][c4 * 4];
        yv[c4*4+0] = (v0.x + v1.x + v2.x + v3.x) * inv;
        yv[c4*4+1] = (v0.y + v1.y + v2.y + v3.y) * inv;
        yv[c4*4+2] = (v0.z + v1.z + v2.z + v3.z) * inv;
        yv[c4*4+3] = (v0.w + v1.w + v2.w + v3.w) * inv;
        float4 p0 = *(const float4*)&ly1p[jo][qo][c4 * 4];
        float4 p1 = *(const float4*)&ly1p[2 + jo][qo][c4 * 4];
        y1v[c4*4+0] = (p0.x + p1.x) * inv1;
        y1v[c4*4+1] = (p0.y + p1.y) * inv1;
        y1v[c4*4+2] = (p0.z + p1.z) * inv1;
        y1v[c4*4+3] = (p0.w + p1.w) * inv1;
    }

    int obase = og * 8;
    const float* xb = x   + ((size_t)(b * C_IN + obase)) * N_POS + n;
    float*       ob = out + ((size_t)(b * C_IN + obase)) * N_POS + n;
    #pragma unroll
    for (int o = 0; o < 8; o++) {
        float acc = Wb[obase + o] + Wzb[obase + o] + xb[(size_t)o * N_POS];
        const float4* w4  = (const float4*)(Ww  + (obase + o) * 32);
        const float4* wz4 = (const float4*)(Wzw + (obase + o) * 32);
        #pragma unroll
        for (int c4 = 0; c4 < 8; c4++) {
            float4 a = w4[c4], z = wz4[c4];
            acc += a.x * yv[c4*4+0] + a.y * yv[c4*4+1] + a.z * yv[c4*4+2] + a.w * yv[c4*4+3];
            acc += z.x * y1v[c4*4+0] + z.y * y1v[c4*4+1] + z.z * y1v[c4*4+2] + z.w * y1v[c4*4+3];
        }
        ob[(size_t)o * N_POS] = acc;
    }
}

extern "C" void kernel_launch(void* const* d_in, const int* in_sizes, int n_in,
                              void* d_out, int out_size, void* d_ws, size_t ws_size,
                              hipStream_t stream) {
    const float* x    = (const float*)d_in[0];
    const float* g_w  = (const float*)d_in[1];
    const float* g_b  = (const float*)d_in[2];
    const float* th_w = (const float*)d_in[3];
    const float* th_b = (const float*)d_in[4];
    const float* ph_w = (const float*)d_in[5];
    const float* ph_b = (const float*)d_in[6];
    const float* W_w  = (const float*)d_in[7];
    const float* W_b  = (const float*)d_in[8];
    const float* Wz_w = (const float*)d_in[9];
    const float* Wz_b = (const float*)d_in[10];
    const float* mb   = (const float*)d_in[11];
    float* out = (float*)d_out;

    char* w = (char*)d_ws;
    ushort* tht = (ushort*)w;                        // 2 MB
    ushort* pht = (ushort*)(w + (2u << 20));         // 2 MB
    ushort* gcn = (ushort*)(w + (4u << 20));         // 2 MB
    ushort* mbt = (ushort*)(w + (6u << 20));         // 16 KB
    ushort* mbb = (ushort*)(w + (6u << 20) + 16384); // 16 KB

    proj_kernel<<<dim3(256, 6), 128, 0, stream>>>(x, g_w, g_b, th_w, th_b,
                                                  ph_w, ph_b, mb,
                                                  gcn, tht, pht, mbt, mbb);
    attn_fused<<<512, 512, 0, stream>>>(tht, pht, gcn, mbt, mbb, x,
                                        W_w, W_b, Wz_w, Wz_b, out);
}